// Round 1
// baseline (487.430 us; speedup 1.0000x reference)
//
#include <hip/hip_runtime.h>

// ---------------------------------------------------------------------------
// SHCA round 5:
//  - NEW: fused flash-style attention (logits + softmax + attn@V in one
//    kernel). exp without max-subtraction (logits bounded ~±5), deferred
//    rowsum normalization -> no online rescale needed. Removes the 33.5MB
//    logit round-trips and the softmax kernel (~125us -> ~35us predicted).
//  - batch<->XCD affinity (block id&7 = batch) so per-XCD L2 holds one
//    batch's xk/xvt/yq working set.
//  - align/mask streamed via global_load_lds, single-buffer, prefetched
//    during the PV phase.
//  - E tile in XOR-swizzled LDS (conflict-free ds_read_b128 A-frags).
//  - unchanged: cvt kernels, KV/yq/final GEMMs, transpose_xv.
// ---------------------------------------------------------------------------

#define FMAXF 3.402823466e38f

typedef __attribute__((ext_vector_type(8))) __bf16 bf16x8;
typedef __attribute__((ext_vector_type(4))) float f32x4;

static __device__ __forceinline__ short f2b(float f) {
  union { float f; unsigned u; } x; x.f = f;
  unsigned r = (x.u + 0x7FFFu + ((x.u >> 16) & 1u)) >> 16;
  return (short)r;
}

static __device__ __forceinline__ void gl_lds16(const short* g, short* l) {
  __builtin_amdgcn_global_load_lds(
      (const __attribute__((address_space(1))) void*)g,
      (__attribute__((address_space(3))) void*)l, 16, 0, 0);
}

// ---------------- epilogue functors -----------------------------------------

struct EpiKV {
  static constexpr bool staged = true;
  short* xk; short* xv; const float* kb; const float* vb;
  __device__ float bias_at(int n) const { return n < 512 ? kb[n] : vb[n - 512]; }
  __device__ void store(int bz, int m, int n, int4 v) const {
    int b = m & 7; long x = m >> 3;
    if (n < 512) *(int4*)(xk + ((long)b * 2048 + x) * 512 + n) = v;
    else         *(int4*)(xv + ((long)b * 2048 + x) * 512 + (n - 512)) = v;
  }
};

struct EpiYq {
  static constexpr bool staged = true;
  short* out; const float* bias;
  __device__ float bias_at(int n) const { return bias[n]; }
  __device__ void store(int bz, int m, int n, int4 v) const {
    *(int4*)(out + (((long)(m & 7)) * 1024 + (m >> 3)) * 512 + n) = v;
  }
};

struct EpiOut {  // fp32 output, direct stores
  static constexpr bool staged = false;
  float* out; const float* bias;
  __device__ void direct(int bz, int m, int n, float v) const {
    out[(long)m * 1024 + n] = v + bias[n];
  }
};

// ---------------- TM x 128 bf16 MFMA GEMM (A x B^T), BK=64 ------------------
template <int TM, typename Epi>
__global__ __launch_bounds__(256) void gemm_mt(
    const short* __restrict__ A, long sAb, int lda,
    const short* __restrict__ B, long sBb, int ldb,
    int K, int tlog, Epi epi) {
  constexpr int R = TM + 128;
  constexpr int SEGS = R / 32;
  constexpr int LDSN = (R * 64 > TM * 128) ? R * 64 : TM * 128;
  __shared__ short S[LDSN];

  const int tid = threadIdx.x;
  const int lane = tid & 63, wave = tid >> 6;
  const int bz = blockIdx.z;

  const int id = blockIdx.x;
  const int xcd = id & 7;
  const int rr = id >> 3;
  const int n0 = (rr & ((1 << tlog) - 1)) * 128;
  const int m0 = (((rr >> tlog) << 3) + xcd) * TM;

  const short* gp[SEGS];
#pragma unroll
  for (int t = 0; t < SEGS; t++) {
    int slot = t * 256 + tid;
    int row = slot >> 3;
    int gcol = ((slot & 7) ^ (row & 7)) * 8;
    gp[t] = (row < TM)
                ? A + (long)bz * sAb + (long)(m0 + row) * lda + gcol
                : B + (long)bz * sBb + (long)(n0 + row - TM) * ldb + gcol;
  }

  const int wm = (TM == 128) ? (wave & 1) * 64 : 0;
  const int wn = (TM == 128) ? (wave >> 1) * 64 : wave * 32;
  constexpr int MI = 4;
  constexpr int MJ = (TM == 128) ? 4 : 2;
  const int quad = lane >> 4, l16 = lane & 15;
  const int xr = l16 & 7;

  f32x4 acc[MI][MJ] = {};

  for (int k0 = 0; k0 < K; k0 += 64) {
#pragma unroll
    for (int t = 0; t < SEGS; t++)
      gl_lds16(gp[t] + k0, S + (t * 256 + tid) * 8);
    __syncthreads();

#pragma unroll
    for (int kk = 0; kk < 2; kk++) {
      union { int4 v; bf16x8 f; } a[MI], b[MJ];
      const int g = ((kk << 2) + quad);
#pragma unroll
      for (int i = 0; i < MI; i++)
        a[i].v = *(const int4*)(S + (wm + i * 16 + l16) * 64 + (g ^ xr) * 8);
#pragma unroll
      for (int j = 0; j < MJ; j++)
        b[j].v = *(const int4*)(S + (TM + wn + j * 16 + l16) * 64 + (g ^ xr) * 8);
#pragma unroll
      for (int i = 0; i < MI; i++)
#pragma unroll
        for (int j = 0; j < MJ; j++)
          acc[i][j] = __builtin_amdgcn_mfma_f32_16x16x32_bf16(a[i].f, b[j].f,
                                                              acc[i][j], 0, 0, 0);
    }
    __syncthreads();
  }

  if constexpr (Epi::staged) {
#pragma unroll
    for (int j = 0; j < MJ; j++) {
      const int c = wn + j * 16 + l16;
      const float bj = epi.bias_at(n0 + c);
#pragma unroll
      for (int i = 0; i < MI; i++)
#pragma unroll
        for (int r = 0; r < 4; r++)
          S[(wm + i * 16 + quad * 4 + r) * 128 + c] = f2b(acc[i][j][r] + bj);
    }
    __syncthreads();
#pragma unroll
    for (int t = 0; t < TM / 16; t++) {
      int c = t * 256 + tid;
      int row = c >> 4, colc = (c & 15) * 8;
      int4 v = *(const int4*)(S + row * 128 + colc);
      epi.store(bz, m0 + row, n0 + colc, v);
    }
  } else {
#pragma unroll
    for (int i = 0; i < MI; i++)
#pragma unroll
      for (int j = 0; j < MJ; j++)
#pragma unroll
        for (int r = 0; r < 4; r++)
          epi.direct(bz, m0 + wm + i * 16 + quad * 4 + r,
                     n0 + wn + j * 16 + l16, acc[i][j][r]);
  }
}

// ---------------- converts --------------------------------------------------
__global__ __launch_bounds__(256) void cvt_f32_bf16(const float* __restrict__ in,
                                                    short* __restrict__ out,
                                                    long n4) {
  long i = (long)blockIdx.x * 256 + threadIdx.x;
  if (i >= n4) return;
  float4 f = ((const float4*)in)[i];
  union { short s[4]; long long v; } o;
  o.s[0] = f2b(f.x); o.s[1] = f2b(f.y); o.s[2] = f2b(f.z); o.s[3] = f2b(f.w);
  ((long long*)out)[i] = o.v;
}

__global__ __launch_bounds__(256) void cvt_weights(
    const float* __restrict__ xk_w, const float* __restrict__ xv_w,
    const float* __restrict__ yq_w, const float* __restrict__ yw_w,
    short* __restrict__ wkv, short* __restrict__ wyq, short* __restrict__ wyw) {
  long i = (long)blockIdx.x * 256 + threadIdx.x;
  const float* src; long long* dst; long off;
  if (i < 131072)      { src = xk_w; dst = (long long*)wkv; off = i; }
  else if (i < 262144) { src = xv_w; dst = (long long*)wkv + 131072; off = i - 131072; }
  else if (i < 393216) { src = yq_w; dst = (long long*)wyq; off = i - 262144; }
  else                 { src = yw_w; dst = (long long*)wyw; off = i - 393216; }
  float4 f = ((const float4*)src)[off];
  union { short s[4]; long long v; } o;
  o.s[0] = f2b(f.x); o.s[1] = f2b(f.y); o.s[2] = f2b(f.z); o.s[3] = f2b(f.w);
  dst[off] = o.v;
}

__global__ __launch_bounds__(256) void cvt_y_concat(const float* __restrict__ in,
                                                    short* __restrict__ out) {
  long idx = (long)blockIdx.x * 256 + threadIdx.x;
  long row = idx >> 8;
  int c = (int)(idx & 255) << 2;
  float4 f = *(const float4*)(in + row * 1024 + c);
  union { short s[4]; unsigned long long v; } o;
  o.s[0] = f2b(f.x); o.s[1] = f2b(f.y); o.s[2] = f2b(f.z); o.s[3] = f2b(f.w);
  *(unsigned long long*)(out + row * 1536 + c) = o.v;
}

// ---------------- xv[b][x][h] -> xvt[b][h][x] -------------------------------
__global__ __launch_bounds__(256) void transpose_xv(const short* __restrict__ xv,
                                                    short* __restrict__ xvt) {
  __shared__ short t[32][36];
  const int b = blockIdx.z;
  const long x0 = (long)blockIdx.x * 32, h0 = (long)blockIdx.y * 32;
  const int r = threadIdx.x >> 3, c = (threadIdx.x & 7) * 4;
  const short* src = xv + ((long)b * 2048 + x0 + r) * 512 + h0 + c;
  *(int2*)&t[r][c] = *(const int2*)src;
  __syncthreads();
  union { short s[4]; int2 v; } o;
  o.s[0] = t[c + 0][r]; o.s[1] = t[c + 1][r];
  o.s[2] = t[c + 2][r]; o.s[3] = t[c + 3][r];
  short* dst = xvt + ((long)b * 512 + h0 + r) * 2048 + x0 + c;
  *(int2*)dst = o.v;
}

// ---------------- fused attention ------------------------------------------
// Per block: batch b = id&7 (XCD affinity), 32 y-rows, 8 waves, 512 threads.
// For each x-tile of 128: S = yq@xk^T (frags from L1/L2), E = exp(S*scale +
// g*align or -inf), E -> swizzled LDS, O += E @ xvt (B-frags from L2).
// rowsum deferred to epilogue (no max subtraction: logits bounded ~ +-5).
__global__ __launch_bounds__(512) void flash_attn(
    const short* __restrict__ yq, const short* __restrict__ xk,
    const short* __restrict__ xvt, const float* __restrict__ align,
    const int* __restrict__ mask, const float* __restrict__ alw,
    short* __restrict__ concat) {
  __shared__ __align__(16) char lds[41984];
  float* As = (float*)lds;              // [32][128] align tile, 16KB
  int*   Ms = (int*)(lds + 16384);      // [32][128] mask tile,  16KB
  short* Es = (short*)(lds + 32768);    // [32][128] E tile (swizzled), 8KB
  float* RS = (float*)(lds + 40960);    // [8][32] per-wave rowsums, 1KB

  const int tid = threadIdx.x;
  const int lane = tid & 63, wave = tid >> 6;
  const int quad = lane >> 4, l16 = lane & 15;
  const int id = blockIdx.x;
  const int b = id & 7, y0 = (id >> 3) * 32;

  const float g = 1.0f / (1.0f + __expf(-alw[0]));
  const float scale = 0.04419417382415922f;  // 1/sqrt(512)

  const short* yqb = yq + (long)b * 1024 * 512;
  const short* xkb = xk + (long)b * 2048 * 512;
  const short* xvb = xvt + (long)b * 512 * 2048;
  const float* alb = align + ((long)b * 1024 + y0) * 2048;
  const int*   mkb = mask + ((long)b * 1024 + y0) * 2048;

  // stage align+mask tile t into As/Ms (linear gl_lds slots)
  auto stage = [&](int t) {
    const long x0 = (long)t * 128;
#pragma unroll
    for (int u = 0; u < 2; u++) {
      int slot = u * 512 + tid;             // 16B slots; 32 per row
      int row = slot >> 5, gcol = (slot & 31) * 4;
      gl_lds16((const short*)(alb + (long)row * 2048 + x0 + gcol),
               (short*)(As + slot * 4));
      gl_lds16((const short*)(mkb + (long)row * 2048 + x0 + gcol),
               (short*)(Ms + slot * 4));
    }
  };

  f32x4 acc[2][4] = {};   // PV accumulator: rows 2x16, d-cols wave*64 + 4x16
  float rs[8] = {};       // per-lane partial rowsums

  stage(0);
  asm volatile("s_waitcnt vmcnt(0)" ::: "memory");
  __syncthreads();

#pragma unroll 1
  for (int t = 0; t < 16; t++) {
    const int x0 = t * 128;
    // ---- QK^T: S slice 32 rows x 16 cols per wave, K=512 ----
    f32x4 s0 = {}, s1 = {};
    const short* ap0 = yqb + (long)(y0 + l16) * 512 + quad * 8;
    const short* ap1 = ap0 + 16 * 512;
    const short* bp  = xkb + (long)(x0 + wave * 16 + l16) * 512 + quad * 8;
#pragma unroll
    for (int kk = 0; kk < 16; kk++) {
      union { int4 v; bf16x8 f; } a0, a1, bb;
      a0.v = *(const int4*)(ap0 + kk * 32);
      a1.v = *(const int4*)(ap1 + kk * 32);
      bb.v = *(const int4*)(bp + kk * 32);
      s0 = __builtin_amdgcn_mfma_f32_16x16x32_bf16(a0.f, bb.f, s0, 0, 0, 0);
      s1 = __builtin_amdgcn_mfma_f32_16x16x32_bf16(a1.f, bb.f, s1, 0, 0, 0);
    }
    // ---- E = exp(S*scale + bias); write swizzled Es; accumulate rowsums ----
    const int col = wave * 16 + l16;        // 0..127 in tile
    const int cg = col >> 3;                // 16B granule 0..15
#pragma unroll
    for (int i = 0; i < 2; i++) {
#pragma unroll
      for (int r = 0; r < 4; r++) {
        int row = i * 16 + quad * 4 + r;
        float sv = i ? s1[r] : s0[r];
        float bias = Ms[row * 128 + col] ? -FMAXF : g * As[row * 128 + col];
        float e = __expf(fmaf(sv, scale, bias));   // masked: exp(-inf)=0
        rs[i * 4 + r] += e;
        int sg = cg ^ (row & 7);
        Es[row * 128 + sg * 8 + (col & 7)] = f2b(e);
      }
    }
    __syncthreads();
    if (t < 15) stage(t + 1);   // prefetch next align/mask under PV
    // ---- PV: acc += E(32x128) @ xvt-slice(64 d-cols per wave) ----
    const int d0 = wave * 64;
    const short* vp = xvb + (long)(d0 + l16) * 2048 + x0 + quad * 8;
#pragma unroll
    for (int kk = 0; kk < 4; kk++) {
      union { int4 v; bf16x8 f; } ea[2], vb[4];
      const int gi = kk * 4 + quad;
#pragma unroll
      for (int i = 0; i < 2; i++) {
        int row = i * 16 + l16;
        int sg = gi ^ (row & 7);
        ea[i].v = *(const int4*)(Es + row * 128 + sg * 8);
      }
#pragma unroll
      for (int j = 0; j < 4; j++)
        vb[j].v = *(const int4*)(vp + (long)j * 16 * 2048 + kk * 32);
#pragma unroll
      for (int i = 0; i < 2; i++)
#pragma unroll
        for (int j = 0; j < 4; j++)
          acc[i][j] = __builtin_amdgcn_mfma_f32_16x16x32_bf16(
              ea[i].f, vb[j].f, acc[i][j], 0, 0, 0);
    }
    asm volatile("s_waitcnt vmcnt(0)" ::: "memory");  // drain gl_lds prefetch
    __syncthreads();
  }

  // ---- rowsum reduce: across 16 lanes (cols in wave), then across waves ----
#pragma unroll
  for (int k = 0; k < 8; k++) {
#pragma unroll
    for (int off = 1; off < 16; off <<= 1)
      rs[k] += __shfl_xor(rs[k], off);
  }
  if (l16 == 0) {
#pragma unroll
    for (int i = 0; i < 2; i++)
#pragma unroll
      for (int r = 0; r < 4; r++)
        RS[wave * 32 + i * 16 + quad * 4 + r] = rs[i * 4 + r];
  }
  __syncthreads();
  float inv[2][4];
#pragma unroll
  for (int i = 0; i < 2; i++)
#pragma unroll
    for (int r = 0; r < 4; r++) {
      int row = i * 16 + quad * 4 + r;
      float s = 0.0f;
#pragma unroll
      for (int w = 0; w < 8; w++) s += RS[w * 32 + row];
      inv[i][r] = 1.0f / s;
    }

  // ---- normalize + stage output in LDS (swizzled), coalesced int4 stores ---
  short* Os = (short*)lds;  // [32][512] bf16, 32KB (reuses As/Ms, now dead)
  const int d0 = wave * 64;
#pragma unroll
  for (int i = 0; i < 2; i++)
#pragma unroll
    for (int j = 0; j < 4; j++) {
      int colb = d0 + j * 16 + l16;
#pragma unroll
      for (int r = 0; r < 4; r++) {
        int row = i * 16 + quad * 4 + r;
        int sg = (colb >> 3) ^ (row & 7);
        Os[row * 512 + sg * 8 + (colb & 7)] = f2b(acc[i][j][r] * inv[i][r]);
      }
    }
  __syncthreads();
#pragma unroll
  for (int u = 0; u < 4; u++) {
    int slot = u * 512 + tid;
    int row = slot >> 6, gg = slot & 63;
    int sg = gg ^ (row & 7);
    int4 v = *(const int4*)(Os + row * 512 + sg * 8);
    *(int4*)(concat + ((long)(y0 + row) * 8 + b) * 1536 + 1024 + gg * 8) = v;
  }
}

// ---------------------------------------------------------------------------

extern "C" void kernel_launch(void* const* d_in, const int* in_sizes, int n_in,
                              void* d_out, int out_size, void* d_ws, size_t ws_size,
                              hipStream_t stream) {
  const float* X    = (const float*)d_in[0];
  const float* Y    = (const float*)d_in[1];
  const float* alig = (const float*)d_in[2];
  const int*   mask = (const int*)d_in[3];
  const float* Xk_w = (const float*)d_in[4];
  const float* Xk_b = (const float*)d_in[5];
  const float* Xv_w = (const float*)d_in[6];
  const float* Xv_b = (const float*)d_in[7];
  const float* Yq_w = (const float*)d_in[8];
  const float* Yq_b = (const float*)d_in[9];
  const float* Yw_w = (const float*)d_in[10];
  const float* Yw_b = (const float*)d_in[11];
  const float* alw  = (const float*)d_in[12];
  float* out = (float*)d_out;

  char* ws = (char*)d_ws;
  short* xbf    = (short*)(ws + 0);          // 33.5MB X as bf16
  short* xk     = (short*)(ws + 33554432);   // 16.8MB [8][2048][512]
  short* xv     = (short*)(ws + 50331648);   // 16.8MB [8][2048][512]
  short* xvt    = (short*)(ws + 67108864);   // 16.8MB [8][512][2048]
  short* yq     = (short*)(ws + 83886080);   //  8.4MB [8][1024][512]
  short* concat = (short*)(ws + 92274688);   // 25.2MB [8192][1536]
  short* wkv    = (short*)(ws + 117440512);  //  2.1MB [1024][1024] (Xk|Xv)
  short* wyq    = (short*)(ws + 119537664);  //  1.0MB [512][1024]
  short* wyw    = (short*)(ws + 120586240);  //  3.1MB [1024][1536]

  // --- converts ---
  cvt_f32_bf16<<<16384, 256, 0, stream>>>(X, xbf, 4194304);
  cvt_y_concat<<<8192, 256, 0, stream>>>(Y, concat);
  cvt_weights<<<3072, 256, 0, stream>>>(Xk_w, Xv_w, Yq_w, Yw_w, wkv, wyq, wyw);

  // --- fused xk/xv projection: (16384 x 1024) x (1024 x 1024)^T ---
  gemm_mt<128, EpiKV><<<dim3(1024, 1, 1), 256, 0, stream>>>(
      xbf, 0, 1024, wkv, 0, 1024, 1024, 3, EpiKV{xk, xv, Xk_b, Xv_b});

  // --- yq: concat[:, :1024] (8192 x 1024, ld 1536) x (512 x 1024)^T ---
  gemm_mt<64, EpiYq><<<dim3(512, 1, 1), 256, 0, stream>>>(
      concat, 0, 1536, wyq, 0, 1024, 1024, 2, EpiYq{yq, Yq_b});

  // --- xv -> xvt ---
  transpose_xv<<<dim3(64, 16, 8), 256, 0, stream>>>(xv, xvt);

  // --- fused logits + softmax + attn@V -> concat[:, 1024:] ---
  flash_attn<<<256, 512, 0, stream>>>(yq, xk, xvt, alig, mask, alw, concat);

  // --- final: (8192x1536) x (1024x1536)^T -> fp32 out ---
  gemm_mt<128, EpiOut><<<dim3(512, 1, 1), 256, 0, stream>>>(
      concat, 0, 1536, wyw, 0, 1536, 1536, 3, EpiOut{out, Yw_b});
}